// Round 4
// baseline (225.918 us; speedup 1.0000x reference)
//
#include <hip/hip_runtime.h>
#include <math.h>

#define BHn 16
#define SLEN 4096
#define Dd 64
#define Cc 64
#define NCC 64
#define EPSF 1e-6f
#define PD 65

// ---------------------------------------------------------------------------
// kA: per (head, chunk) UT transform.
//   KT[d][t] = l2norm(k)^T ; SM = g_i*(kn_i.kn_j) lower; wave0/wave1 solve W/U
//   columns in registers (SM reads are wave-uniform broadcasts). Solutions are
//   staged through LDS so global stores are fully coalesced b128.
// ---------------------------------------------------------------------------
__global__ __launch_bounds__(256, 4) void kA(
    const float* __restrict__ kg, const float* __restrict__ vg,
    const float* __restrict__ betag, float* __restrict__ WTg, float* __restrict__ UTg,
    float* __restrict__ wlast, float* __restrict__ ulast)
{
    const int n = blockIdx.x, bh = blockIdx.y, tid = threadIdx.x;
    __shared__ float KT[64 * PD];   // kn^T -> (g*v)^T -> W^T staging
    __shared__ float SM[64 * PD];   // scaled S -> U^T staging
    __shared__ float gl[64];

    const size_t base = ((size_t)bh * SLEN + (size_t)n * Cc) * Dd;

    // issue ALL global loads up front (latency hidden under norm + S phases)
    float4 kv[4], vv[4];
#pragma unroll
    for (int p = 0; p < 4; p++) {
        const int flat = p * 1024 + tid * 4;
        kv[p] = *(const float4*)(kg + base + flat);
        vv[p] = *(const float4*)(vg + base + flat);
    }
    if (tid < 64) {
        const float b = betag[(size_t)bh * SLEN + n * Cc + tid];
        gl[tid] = fminf(fmaxf(b, EPSF), 1.0f - EPSF);
    }
    // KT = kn^T: 16-lane shuffle norms + transposed scalar writes (2 lanes/bank)
#pragma unroll
    for (int p = 0; p < 4; p++) {
        const int flat = p * 1024 + tid * 4;
        const int row = flat >> 6, d0 = flat & 63;
        const float4 a = kv[p];
        float ss = a.x * a.x + a.y * a.y + a.z * a.z + a.w * a.w;
        ss += __shfl_xor(ss, 1); ss += __shfl_xor(ss, 2);
        ss += __shfl_xor(ss, 4); ss += __shfl_xor(ss, 8);
        const float inv = 1.0f / (sqrtf(ss) + EPSF);
        KT[(d0 + 0) * PD + row] = a.x * inv;
        KT[(d0 + 1) * PD + row] = a.y * inv;
        KT[(d0 + 2) * PD + row] = a.z * inv;
        KT[(d0 + 3) * PD + row] = a.w * inv;
    }
    __syncthreads();

    float sol[64];
    if (tid < 64) {
        // wave0: W solve column = KT[tid][:] * g[:] (concurrent with S below)
#pragma unroll
        for (int j4 = 0; j4 < 16; j4++) {
            const float4 t4 = *(const float4*)&KT[tid * PD + j4 * 4];
            sol[j4 * 4 + 0] = t4.x * gl[j4 * 4 + 0];
            sol[j4 * 4 + 1] = t4.y * gl[j4 * 4 + 1];
            sol[j4 * 4 + 2] = t4.z * gl[j4 * 4 + 2];
            sol[j4 * 4 + 3] = t4.w * gl[j4 * 4 + 3];
        }
    } else if (tid < 200) {
        // S lower 4x4 tiles from KT (broadcast b128 reads), rows scaled by g_i
        const int t = tid - 64;
        int ti = (int)((sqrtf(8.0f * (float)t + 1.0f) - 1.0f) * 0.5f);
        while (ti * (ti + 1) / 2 > t) --ti;
        while ((ti + 1) * (ti + 2) / 2 <= t) ++ti;
        const int tj = t - ti * (ti + 1) / 2;
        const int i0 = ti * 4, j0 = tj * 4;
        float sa[4][4];
#pragma unroll
        for (int r = 0; r < 4; r++)
#pragma unroll
            for (int c2 = 0; c2 < 4; c2++) sa[r][c2] = 0.f;
        for (int d = 0; d < 64; d++) {
            const float4 a = *(const float4*)&KT[d * PD + i0];
            const float4 b = *(const float4*)&KT[d * PD + j0];
            const float av[4] = {a.x, a.y, a.z, a.w};
            const float bv[4] = {b.x, b.y, b.z, b.w};
#pragma unroll
            for (int r = 0; r < 4; r++)
#pragma unroll
                for (int c2 = 0; c2 < 4; c2++) sa[r][c2] += av[r] * bv[c2];
        }
#pragma unroll
        for (int r = 0; r < 4; r++) {
            const float gg = gl[i0 + r];
            *(float4*)&SM[(i0 + r) * PD + j0] =
                make_float4(sa[r][0] * gg, sa[r][1] * gg, sa[r][2] * gg, sa[r][3] * gg);
        }
    }
    __syncthreads();

    // overwrite KT with (g*v)^T from the prefetched registers
#pragma unroll
    for (int p = 0; p < 4; p++) {
        const int flat = p * 1024 + tid * 4;
        const int row = flat >> 6, d0 = flat & 63;
        const float gg = gl[row];
        KT[(d0 + 0) * PD + row] = vv[p].x * gg;
        KT[(d0 + 1) * PD + row] = vv[p].y * gg;
        KT[(d0 + 2) * PD + row] = vv[p].z * gg;
        KT[(d0 + 3) * PD + row] = vv[p].w * gg;
    }
    __syncthreads();

    if (tid >= 64 && tid < 128) {
        const int c = tid - 64;   // wave1: U solve column
#pragma unroll
        for (int j4 = 0; j4 < 16; j4++) {
            const float4 t4 = *(const float4*)&KT[c * PD + j4 * 4];
            sol[j4 * 4 + 0] = t4.x; sol[j4 * 4 + 1] = t4.y;
            sol[j4 * 4 + 2] = t4.z; sol[j4 * 4 + 3] = t4.w;
        }
    }
    if (tid < 128) {
        // register forward substitution; SM reads are wave-uniform broadcasts
#pragma unroll
        for (int b = 0; b < 8; b++) {
            const int i0 = b * 8;
            float acc[8];
#pragma unroll
            for (int r = 0; r < 8; r++) acc[r] = sol[i0 + r];
#pragma unroll
            for (int j4 = 0; j4 < 2 * b; j4++) {
                const int j = j4 * 4;
                const float s0 = sol[j + 0], s1 = sol[j + 1];
                const float s2 = sol[j + 2], s3 = sol[j + 3];
#pragma unroll
                for (int r = 0; r < 8; r++) {
                    const float4 m4 = *(const float4*)&SM[(i0 + r) * PD + j];
                    acc[r] -= m4.x * s0 + m4.y * s1 + m4.z * s2 + m4.w * s3;
                }
            }
#pragma unroll
            for (int il = 1; il < 8; il++)
#pragma unroll
                for (int jl = 0; jl < il; jl++)
                    acc[il] -= SM[(i0 + il) * PD + i0 + jl] * acc[jl];
#pragma unroll
            for (int r = 0; r < 8; r++) sol[i0 + r] = acc[r];
        }
    }
    __syncthreads();   // all SM solve-reads done; KT dead

    // stage solutions: wave0 -> KT row, wave1 -> SM row (b128, 2-way banks)
    if (tid < 128) {
        const int c = tid & 63;
        float* dstl = (tid < 64) ? &KT[c * PD] : &SM[c * PD];
#pragma unroll
        for (int j4 = 0; j4 < 16; j4++)
            *(float4*)&dstl[j4 * 4] = make_float4(sol[j4*4+0], sol[j4*4+1],
                                                  sol[j4*4+2], sol[j4*4+3]);
        float* lst = (tid < 64 ? wlast : ulast);
        lst[(size_t)(bh * NCC + n) * 64 + c] = sol[63];
    }
    __syncthreads();

    // coalesced global stores of W^T, U^T
    {
        float* wdst = WTg + (size_t)(bh * NCC + n) * Cc * Dd;
        float* udst = UTg + (size_t)(bh * NCC + n) * Cc * Dd;
#pragma unroll
        for (int p = 0; p < 4; p++) {
            const int flat = p * 1024 + tid * 4;
            const int row = flat >> 6, pos = flat & 63;
            *(float4*)(wdst + flat) = *(const float4*)&KT[row * PD + pos];
            *(float4*)(udst + flat) = *(const float4*)&SM[row * PD + pos];
        }
    }
}

// ---------------------------------------------------------------------------
// kB: chunk-level delta rule (16 blocks). Register solve.
// ---------------------------------------------------------------------------
__global__ __launch_bounds__(256) void kB(
    const float* __restrict__ wlast, const float* __restrict__ ulast,
    float* __restrict__ Uvg)
{
    const int bh = blockIdx.x, tid = threadIdx.x;
    __shared__ float WL[64 * PD];
    __shared__ float UL[64 * PD];
    __shared__ float SM[64 * PD];
    const size_t gbase = (size_t)bh * NCC * 64;

#pragma unroll
    for (int p = 0; p < 4; p++) {
        const int flat = p * 1024 + tid * 4;
        const int m = flat >> 6, d = flat & 63;
        *(float4*)&WL[m * PD + d] = *(const float4*)(wlast + gbase + flat);
        *(float4*)&UL[m * PD + d] = *(const float4*)(ulast + gbase + flat);
    }
    __syncthreads();

    if (tid < 136) {
        int ti = (int)((sqrtf(8.0f * (float)tid + 1.0f) - 1.0f) * 0.5f);
        while (ti * (ti + 1) / 2 > tid) --ti;
        while ((ti + 1) * (ti + 2) / 2 <= tid) ++ti;
        const int tj = tid - ti * (ti + 1) / 2;
        const int i0 = ti * 4, j0 = tj * 4;
        float sa[4][4];
#pragma unroll
        for (int r = 0; r < 4; r++)
#pragma unroll
            for (int c2 = 0; c2 < 4; c2++) sa[r][c2] = 0.f;
        for (int d4 = 0; d4 < 16; d4++) {
            const int d = d4 * 4;
            float4 ar[4], bc[4];
#pragma unroll
            for (int r = 0; r < 4; r++) ar[r] = *(const float4*)&WL[(i0 + r) * PD + d];
#pragma unroll
            for (int c2 = 0; c2 < 4; c2++) bc[c2] = *(const float4*)&WL[(j0 + c2) * PD + d];
#pragma unroll
            for (int r = 0; r < 4; r++)
#pragma unroll
                for (int c2 = 0; c2 < 4; c2++)
                    sa[r][c2] += ar[r].x * bc[c2].x + ar[r].y * bc[c2].y +
                                 ar[r].z * bc[c2].z + ar[r].w * bc[c2].w;
        }
#pragma unroll
        for (int r = 0; r < 4; r++)
            *(float4*)&SM[(i0 + r) * PD + j0] =
                make_float4(sa[r][0], sa[r][1], sa[r][2], sa[r][3]);
    }
    __syncthreads();

    if (tid < 64) {
        const int e = tid;
        float sol[64];
#pragma unroll
        for (int m = 0; m < 64; m++) sol[m] = UL[m * PD + e];
#pragma unroll
        for (int b = 0; b < 8; b++) {
            const int i0 = b * 8;
            float acc[8];
#pragma unroll
            for (int r = 0; r < 8; r++) acc[r] = sol[i0 + r];
#pragma unroll
            for (int j4 = 0; j4 < 2 * b; j4++) {
                const int j = j4 * 4;
                const float s0 = sol[j + 0], s1 = sol[j + 1];
                const float s2 = sol[j + 2], s3 = sol[j + 3];
#pragma unroll
                for (int r = 0; r < 8; r++) {
                    const float4 m4 = *(const float4*)&SM[(i0 + r) * PD + j];
                    acc[r] -= m4.x * s0 + m4.y * s1 + m4.z * s2 + m4.w * s3;
                }
            }
#pragma unroll
            for (int il = 1; il < 8; il++)
#pragma unroll
                for (int jl = 0; jl < il; jl++)
                    acc[il] -= SM[(i0 + il) * PD + i0 + jl] * acc[jl];
#pragma unroll
            for (int r = 0; r < 8; r++) sol[i0 + r] = acc[r];
        }
#pragma unroll
        for (int m = 0; m < 64; m++) Uvg[gbase + (size_t)m * 64 + e] = sol[m];
    }
}

// ---------------------------------------------------------------------------
// kC: output. 512 blocks; block px handles the balanced chunk pair
// (63-px, px) so every block has identical total ph1 work (sum of n = 63).
//   h[d][e] = sum_{m<n} wlast[m][d]*Uval[m][e];  out = qn.*(U - W h) + qn h
// ---------------------------------------------------------------------------
__global__ __launch_bounds__(256, 3) void kC(
    const float* __restrict__ qg, const float* __restrict__ WTg,
    const float* __restrict__ UTg, const float* __restrict__ wlast,
    const float* __restrict__ Uvg, float* __restrict__ outg)
{
    const int px = blockIdx.x, bh = blockIdx.y, tid = threadIdx.x;
    __shared__ float X1[64 * 64];   // wlast[m][d] -> W^T[d][t]   (never transposed-written)
    __shared__ float X2[64 * PD];   // Uval[m][e]  -> qn^T[d][t]  (padded: transposed writes)
    __shared__ float HB[64 * 64];   // h[d][e]
    const size_t lbase = (size_t)bh * NCC * 64;
    const int t0 = (tid >> 4) * 4, e0 = (tid & 15) * 4;

    for (int pass = 0; pass < 2; ++pass) {
        const int n = pass ? px : 63 - px;
        const size_t qbase = ((size_t)bh * SLEN + (size_t)n * Cc) * Dd;
        const size_t wbase = (size_t)(bh * NCC + n) * Cc * Dd;
        if (pass) __syncthreads();   // protect LDS reuse across passes

        float4 qa[4], wt[4];
        float qinv[4];
#pragma unroll
        for (int p = 0; p < 4; p++) {
            const int flat = p * 1024 + tid * 4;
            const int m = flat >> 6, d = flat & 63;
            *(float4*)&X1[m * 64 + d] = *(const float4*)(wlast + lbase + flat);
            *(float4*)&X2[m * PD + d] = *(const float4*)(Uvg + lbase + flat);
            qa[p] = *(const float4*)(qg + qbase + flat);
            float ss = qa[p].x * qa[p].x + qa[p].y * qa[p].y +
                       qa[p].z * qa[p].z + qa[p].w * qa[p].w;
            ss += __shfl_xor(ss, 1); ss += __shfl_xor(ss, 2);
            ss += __shfl_xor(ss, 4); ss += __shfl_xor(ss, 8);
            qinv[p] = 1.0f / (sqrtf(ss) + EPSF);
            wt[p] = *(const float4*)(WTg + wbase + flat);
        }
        __syncthreads();

        // ph1: h tile accumulation over earlier chunks
        float ha[4][4];
#pragma unroll
        for (int r = 0; r < 4; r++)
#pragma unroll
            for (int c2 = 0; c2 < 4; c2++) ha[r][c2] = 0.f;
        for (int m = 0; m < n; m++) {
            const float4 a = *(const float4*)&X1[m * 64 + t0];
            const float4 b = *(const float4*)&X2[m * PD + e0];
            const float av[4] = {a.x, a.y, a.z, a.w};
            const float bv[4] = {b.x, b.y, b.z, b.w};
#pragma unroll
            for (int r = 0; r < 4; r++)
#pragma unroll
                for (int c2 = 0; c2 < 4; c2++) ha[r][c2] += av[r] * bv[c2];
        }
#pragma unroll
        for (int r = 0; r < 4; r++)
            *(float4*)&HB[(t0 + r) * 64 + e0] =
                make_float4(ha[r][0], ha[r][1], ha[r][2], ha[r][3]);
        __syncthreads();

        // rebuild: X1 <- W^T (flat from regs), X2 <- qn^T (transposed writes)
#pragma unroll
        for (int p = 0; p < 4; p++) {
            const int flat = p * 1024 + tid * 4;
            const int d = flat >> 6, t = flat & 63;
            *(float4*)&X1[d * 64 + t] = wt[p];
            const int row = d, d0 = t;   // q decode: (token row, dim d0)
            X2[(d0 + 0) * PD + row] = qa[p].x * qinv[p];
            X2[(d0 + 1) * PD + row] = qa[p].y * qinv[p];
            X2[(d0 + 2) * PD + row] = qa[p].z * qinv[p];
            X2[(d0 + 3) * PD + row] = qa[p].w * qinv[p];
        }
        __syncthreads();

        // ph3: kth = W h, oin = qn h
        float kth[4][4], oin[4][4];
#pragma unroll
        for (int r = 0; r < 4; r++)
#pragma unroll
            for (int c2 = 0; c2 < 4; c2++) { kth[r][c2] = 0.f; oin[r][c2] = 0.f; }
#pragma unroll 4
        for (int d = 0; d < 64; d++) {
            const float4 wv = *(const float4*)&X1[d * 64 + t0];
            const float4 qv = *(const float4*)&X2[d * PD + t0];
            const float4 hv = *(const float4*)&HB[d * 64 + e0];
            const float wa[4] = {wv.x, wv.y, wv.z, wv.w};
            const float qa2[4] = {qv.x, qv.y, qv.z, qv.w};
            const float hv4[4] = {hv.x, hv.y, hv.z, hv.w};
#pragma unroll
            for (int r = 0; r < 4; r++)
#pragma unroll
                for (int c2 = 0; c2 < 4; c2++) {
                    kth[r][c2] += wa[r] * hv4[c2];
                    oin[r][c2] += qa2[r] * hv4[c2];
                }
        }

        // epilogue: U^T tile from global (L2-hot), qn from X2
        float* oc = outg + qbase;
        float o4[4][4];
#pragma unroll
        for (int s = 0; s < 4; s++) {
            const float4 u4 = *(const float4*)(UTg + wbase + (size_t)(e0 + s) * 64 + t0);
            const float4 q4 = *(const float4*)&X2[(e0 + s) * PD + t0];
            o4[0][s] = q4.x * (u4.x - kth[0][s]) + oin[0][s];
            o4[1][s] = q4.y * (u4.y - kth[1][s]) + oin[1][s];
            o4[2][s] = q4.z * (u4.z - kth[2][s]) + oin[2][s];
            o4[3][s] = q4.w * (u4.w - kth[3][s]) + oin[3][s];
        }
#pragma unroll
        for (int r = 0; r < 4; r++)
            *(float4*)(oc + (size_t)(t0 + r) * 64 + e0) =
                make_float4(o4[r][0], o4[r][1], o4[r][2], o4[r][3]);
    }
}

extern "C" void kernel_launch(void* const* d_in, const int* in_sizes, int n_in,
                              void* d_out, int out_size, void* d_ws, size_t ws_size,
                              hipStream_t stream) {
    const float* q    = (const float*)d_in[0];
    const float* k    = (const float*)d_in[1];
    const float* v    = (const float*)d_in[2];
    const float* beta = (const float*)d_in[3];
    float* out = (float*)d_out;

    float* WTg   = (float*)d_ws;                              // [BH][NC][64][64] (W^T)
    float* UTg   = WTg + (size_t)BHn * NCC * Cc * Dd;         // [BH][NC][64][64] (U^T)
    float* wlast = UTg + (size_t)BHn * NCC * Cc * Dd;         // [BH][NC][64]
    float* ulast = wlast + (size_t)BHn * NCC * 64;            // [BH][NC][64]
    float* Uvg   = ulast + (size_t)BHn * NCC * 64;            // [BH][NC][64]

    kA<<<dim3(NCC, BHn), 256, 0, stream>>>(k, v, beta, WTg, UTg, wlast, ulast);
    kB<<<dim3(BHn), 256, 0, stream>>>(wlast, ulast, Uvg);
    kC<<<dim3(32, BHn), 256, 0, stream>>>(q, WTg, UTg, wlast, Uvg, out);
}

// Round 5
// 162.881 us; speedup vs baseline: 1.3870x; 1.3870x over previous
//
#include <hip/hip_runtime.h>
#include <math.h>

#define BHn 16
#define SLEN 4096
#define Dd 64
#define Cc 64
#define NCC 64
#define EPSF 1e-6f
#define PD 65

// ---------------------------------------------------------------------------
// kA: per (head, chunk) UT transform.  (round-3 structure: register solve with
// direct global stores; sol[] never crosses a barrier -> no spill)
//   KT[d][t] = l2norm(k)^T (pad-65 => conflict-free transposed writes)
//   SM[i][j] = g_i * (kn_i . kn_j)   (lower tiles only)
//   Wave0 solves W columns in registers; wave1 solves U columns in registers.
//   Stores W^T,U^T ([dim][token]) + last rows, straight from registers.
// ---------------------------------------------------------------------------
__global__ __launch_bounds__(256, 4) void kA(
    const float* __restrict__ kg, const float* __restrict__ vg,
    const float* __restrict__ betag, float* __restrict__ WTg, float* __restrict__ UTg,
    float* __restrict__ wlast, float* __restrict__ ulast)
{
    const int n = blockIdx.x, bh = blockIdx.y, tid = threadIdx.x;
    __shared__ float KT[64 * PD];   // kn^T, then (g*v)^T
    __shared__ float SM[64 * PD];
    __shared__ float gl[64];

    const size_t base = ((size_t)bh * SLEN + (size_t)n * Cc) * Dd;

    if (tid < 64) {
        const float b = betag[(size_t)bh * SLEN + n * Cc + tid];
        gl[tid] = fminf(fmaxf(b, EPSF), 1.0f - EPSF);
    }
    // build KT = kn^T : coalesced float4 row loads, 16-lane norm, transposed scalar
    // writes (bank = (d+t)%32, exactly 2 lanes/bank => free)
#pragma unroll
    for (int p = 0; p < 4; p++) {
        const int flat = p * 1024 + tid * 4;
        const int row = flat >> 6, d0 = flat & 63;
        const float4 a = *(const float4*)(kg + base + flat);
        float ss = a.x * a.x + a.y * a.y + a.z * a.z + a.w * a.w;
        ss += __shfl_xor(ss, 1); ss += __shfl_xor(ss, 2);
        ss += __shfl_xor(ss, 4); ss += __shfl_xor(ss, 8);
        const float inv = 1.0f / (sqrtf(ss) + EPSF);
        KT[(d0 + 0) * PD + row] = a.x * inv;
        KT[(d0 + 1) * PD + row] = a.y * inv;
        KT[(d0 + 2) * PD + row] = a.z * inv;
        KT[(d0 + 3) * PD + row] = a.w * inv;
    }
    __syncthreads();

    float sol[64];
    if (tid < 64) {
        // wave0: load W solve column = KT[tid][:] * g[:]  (runs concurrent with S)
#pragma unroll
        for (int j4 = 0; j4 < 16; j4++) {
            const float4 t4 = *(const float4*)&KT[tid * PD + j4 * 4];
            sol[j4 * 4 + 0] = t4.x * gl[j4 * 4 + 0];
            sol[j4 * 4 + 1] = t4.y * gl[j4 * 4 + 1];
            sol[j4 * 4 + 2] = t4.z * gl[j4 * 4 + 2];
            sol[j4 * 4 + 3] = t4.w * gl[j4 * 4 + 3];
        }
    } else if (tid < 200) {
        // threads 64..199: S lower 4x4 tiles from KT; rows scaled by g_i
        const int t = tid - 64;
        int ti = (int)((sqrtf(8.0f * (float)t + 1.0f) - 1.0f) * 0.5f);
        while (ti * (ti + 1) / 2 > t) --ti;
        while ((ti + 1) * (ti + 2) / 2 <= t) ++ti;
        const int tj = t - ti * (ti + 1) / 2;
        const int i0 = ti * 4, j0 = tj * 4;
        float sa[4][4];
#pragma unroll
        for (int r = 0; r < 4; r++)
#pragma unroll
            for (int c2 = 0; c2 < 4; c2++) sa[r][c2] = 0.f;
        for (int d = 0; d < 64; d++) {
            const float4 a = *(const float4*)&KT[d * PD + i0];
            const float4 b = *(const float4*)&KT[d * PD + j0];
            const float av[4] = {a.x, a.y, a.z, a.w};
            const float bv[4] = {b.x, b.y, b.z, b.w};
#pragma unroll
            for (int r = 0; r < 4; r++)
#pragma unroll
                for (int c2 = 0; c2 < 4; c2++) sa[r][c2] += av[r] * bv[c2];
        }
#pragma unroll
        for (int r = 0; r < 4; r++) {
            const float gg = gl[i0 + r];
            *(float4*)&SM[(i0 + r) * PD + j0] =
                make_float4(sa[r][0] * gg, sa[r][1] * gg, sa[r][2] * gg, sa[r][3] * gg);
        }
    }
    __syncthreads();

    // overwrite KT with (g*v)^T
#pragma unroll
    for (int p = 0; p < 4; p++) {
        const int flat = p * 1024 + tid * 4;
        const int row = flat >> 6, d0 = flat & 63;
        const float4 a = *(const float4*)(vg + base + flat);
        const float gg = gl[row];
        KT[(d0 + 0) * PD + row] = a.x * gg;
        KT[(d0 + 1) * PD + row] = a.y * gg;
        KT[(d0 + 2) * PD + row] = a.z * gg;
        KT[(d0 + 3) * PD + row] = a.w * gg;
    }
    __syncthreads();

    if (tid >= 64 && tid < 128) {
        // wave1: load U solve column = (g*v)^T row
        const int c = tid - 64;
#pragma unroll
        for (int j4 = 0; j4 < 16; j4++) {
            const float4 t4 = *(const float4*)&KT[c * PD + j4 * 4];
            sol[j4 * 4 + 0] = t4.x; sol[j4 * 4 + 1] = t4.y;
            sol[j4 * 4 + 2] = t4.z; sol[j4 * 4 + 3] = t4.w;
        }
    }
    if (tid < 128) {
        const int c = tid & 63;
        // register forward substitution; SM reads are wave-uniform broadcasts
#pragma unroll
        for (int b = 0; b < 8; b++) {
            const int i0 = b * 8;
            float acc[8];
#pragma unroll
            for (int r = 0; r < 8; r++) acc[r] = sol[i0 + r];
#pragma unroll
            for (int j4 = 0; j4 < 2 * b; j4++) {
                const int j = j4 * 4;
                const float s0 = sol[j + 0], s1 = sol[j + 1];
                const float s2 = sol[j + 2], s3 = sol[j + 3];
#pragma unroll
                for (int r = 0; r < 8; r++) {
                    const float4 m4 = *(const float4*)&SM[(i0 + r) * PD + j];
                    acc[r] -= m4.x * s0 + m4.y * s1 + m4.z * s2 + m4.w * s3;
                }
            }
#pragma unroll
            for (int il = 1; il < 8; il++)
#pragma unroll
                for (int jl = 0; jl < il; jl++)
                    acc[il] -= SM[(i0 + il) * PD + i0 + jl] * acc[jl];
#pragma unroll
            for (int r = 0; r < 8; r++) sol[i0 + r] = acc[r];
        }
        // stores straight from registers: row c of W^T/U^T ([dim][token])
        float* dst = (tid < 64 ? WTg : UTg) +
                     (size_t)(bh * NCC + n) * Cc * Dd + (size_t)c * 64;
#pragma unroll
        for (int j4 = 0; j4 < 16; j4++)
            *(float4*)(dst + j4 * 4) = make_float4(sol[j4 * 4 + 0], sol[j4 * 4 + 1],
                                                   sol[j4 * 4 + 2], sol[j4 * 4 + 3]);
        float* lst = (tid < 64 ? wlast : ulast);
        lst[(size_t)(bh * NCC + n) * 64 + c] = sol[63];
    }
}

// ---------------------------------------------------------------------------
// kB: chunk-level delta rule (16 blocks). Register solve.
// ---------------------------------------------------------------------------
__global__ __launch_bounds__(256) void kB(
    const float* __restrict__ wlast, const float* __restrict__ ulast,
    float* __restrict__ Uvg)
{
    const int bh = blockIdx.x, tid = threadIdx.x;
    __shared__ float WL[64 * PD];
    __shared__ float UL[64 * PD];
    __shared__ float SM[64 * PD];
    const size_t gbase = (size_t)bh * NCC * 64;

#pragma unroll
    for (int p = 0; p < 4; p++) {
        const int flat = p * 1024 + tid * 4;
        const int m = flat >> 6, d = flat & 63;
        *(float4*)&WL[m * PD + d] = *(const float4*)(wlast + gbase + flat);
        *(float4*)&UL[m * PD + d] = *(const float4*)(ulast + gbase + flat);
    }
    __syncthreads();

    if (tid < 136) {
        int ti = (int)((sqrtf(8.0f * (float)tid + 1.0f) - 1.0f) * 0.5f);
        while (ti * (ti + 1) / 2 > tid) --ti;
        while ((ti + 1) * (ti + 2) / 2 <= tid) ++ti;
        const int tj = tid - ti * (ti + 1) / 2;
        const int i0 = ti * 4, j0 = tj * 4;
        float sa[4][4];
#pragma unroll
        for (int r = 0; r < 4; r++)
#pragma unroll
            for (int c2 = 0; c2 < 4; c2++) sa[r][c2] = 0.f;
        for (int d4 = 0; d4 < 16; d4++) {
            const int d = d4 * 4;
            float4 ar[4], bc[4];
#pragma unroll
            for (int r = 0; r < 4; r++) ar[r] = *(const float4*)&WL[(i0 + r) * PD + d];
#pragma unroll
            for (int c2 = 0; c2 < 4; c2++) bc[c2] = *(const float4*)&WL[(j0 + c2) * PD + d];
#pragma unroll
            for (int r = 0; r < 4; r++)
#pragma unroll
                for (int c2 = 0; c2 < 4; c2++)
                    sa[r][c2] += ar[r].x * bc[c2].x + ar[r].y * bc[c2].y +
                                 ar[r].z * bc[c2].z + ar[r].w * bc[c2].w;
        }
#pragma unroll
        for (int r = 0; r < 4; r++)
            *(float4*)&SM[(i0 + r) * PD + j0] =
                make_float4(sa[r][0], sa[r][1], sa[r][2], sa[r][3]);
    }
    __syncthreads();

    if (tid < 64) {
        const int e = tid;
        float sol[64];
#pragma unroll
        for (int m = 0; m < 64; m++) sol[m] = UL[m * PD + e];
#pragma unroll
        for (int b = 0; b < 8; b++) {
            const int i0 = b * 8;
            float acc[8];
#pragma unroll
            for (int r = 0; r < 8; r++) acc[r] = sol[i0 + r];
#pragma unroll
            for (int j4 = 0; j4 < 2 * b; j4++) {
                const int j = j4 * 4;
                const float s0 = sol[j + 0], s1 = sol[j + 1];
                const float s2 = sol[j + 2], s3 = sol[j + 3];
#pragma unroll
                for (int r = 0; r < 8; r++) {
                    const float4 m4 = *(const float4*)&SM[(i0 + r) * PD + j];
                    acc[r] -= m4.x * s0 + m4.y * s1 + m4.z * s2 + m4.w * s3;
                }
            }
#pragma unroll
            for (int il = 1; il < 8; il++)
#pragma unroll
                for (int jl = 0; jl < il; jl++)
                    acc[il] -= SM[(i0 + il) * PD + i0 + jl] * acc[jl];
#pragma unroll
            for (int r = 0; r < 8; r++) sol[i0 + r] = acc[r];
        }
#pragma unroll
        for (int m = 0; m < 64; m++) Uvg[gbase + (size_t)m * 64 + e] = sol[m];
    }
}

// ---------------------------------------------------------------------------
// kC: output. 512 blocks; block px handles the balanced chunk pair
// (63-px, px) so every block has identical total ph1 work (sum of n = 63).
//   h[d][e] = sum_{m<n} wlast[m][d]*Uval[m][e];  out = qn.*(U - W h) + qn h
// ---------------------------------------------------------------------------
__global__ __launch_bounds__(256, 3) void kC(
    const float* __restrict__ qg, const float* __restrict__ WTg,
    const float* __restrict__ UTg, const float* __restrict__ wlast,
    const float* __restrict__ Uvg, float* __restrict__ outg)
{
    const int px = blockIdx.x, bh = blockIdx.y, tid = threadIdx.x;
    __shared__ float X1[64 * 64];   // wlast[m][d] -> W^T[d][t]   (never transposed-written)
    __shared__ float X2[64 * PD];   // Uval[m][e]  -> qn^T[d][t]  (padded: transposed writes)
    __shared__ float HB[64 * 64];   // h[d][e]
    const size_t lbase = (size_t)bh * NCC * 64;
    const int t0 = (tid >> 4) * 4, e0 = (tid & 15) * 4;

    for (int pass = 0; pass < 2; ++pass) {
        const int n = pass ? px : 63 - px;
        const size_t qbase = ((size_t)bh * SLEN + (size_t)n * Cc) * Dd;
        const size_t wbase = (size_t)(bh * NCC + n) * Cc * Dd;
        if (pass) __syncthreads();   // protect LDS reuse across passes

        float4 qa[4], wt[4];
        float qinv[4];
#pragma unroll
        for (int p = 0; p < 4; p++) {
            const int flat = p * 1024 + tid * 4;
            const int m = flat >> 6, d = flat & 63;
            *(float4*)&X1[m * 64 + d] = *(const float4*)(wlast + lbase + flat);
            *(float4*)&X2[m * PD + d] = *(const float4*)(Uvg + lbase + flat);
            qa[p] = *(const float4*)(qg + qbase + flat);
            float ss = qa[p].x * qa[p].x + qa[p].y * qa[p].y +
                       qa[p].z * qa[p].z + qa[p].w * qa[p].w;
            ss += __shfl_xor(ss, 1); ss += __shfl_xor(ss, 2);
            ss += __shfl_xor(ss, 4); ss += __shfl_xor(ss, 8);
            qinv[p] = 1.0f / (sqrtf(ss) + EPSF);
            wt[p] = *(const float4*)(WTg + wbase + flat);
        }
        __syncthreads();

        // ph1: h tile accumulation over earlier chunks
        float ha[4][4];
#pragma unroll
        for (int r = 0; r < 4; r++)
#pragma unroll
            for (int c2 = 0; c2 < 4; c2++) ha[r][c2] = 0.f;
        for (int m = 0; m < n; m++) {
            const float4 a = *(const float4*)&X1[m * 64 + t0];
            const float4 b = *(const float4*)&X2[m * PD + e0];
            const float av[4] = {a.x, a.y, a.z, a.w};
            const float bv[4] = {b.x, b.y, b.z, b.w};
#pragma unroll
            for (int r = 0; r < 4; r++)
#pragma unroll
                for (int c2 = 0; c2 < 4; c2++) ha[r][c2] += av[r] * bv[c2];
        }
#pragma unroll
        for (int r = 0; r < 4; r++)
            *(float4*)&HB[(t0 + r) * 64 + e0] =
                make_float4(ha[r][0], ha[r][1], ha[r][2], ha[r][3]);
        __syncthreads();

        // rebuild: X1 <- W^T (flat from regs), X2 <- qn^T (transposed writes)
#pragma unroll
        for (int p = 0; p < 4; p++) {
            const int flat = p * 1024 + tid * 4;
            const int d = flat >> 6, t = flat & 63;
            *(float4*)&X1[d * 64 + t] = wt[p];
            const int row = d, d0 = t;   // q decode: (token row, dim d0)
            X2[(d0 + 0) * PD + row] = qa[p].x * qinv[p];
            X2[(d0 + 1) * PD + row] = qa[p].y * qinv[p];
            X2[(d0 + 2) * PD + row] = qa[p].z * qinv[p];
            X2[(d0 + 3) * PD + row] = qa[p].w * qinv[p];
        }
        __syncthreads();

        // ph3: kth = W h, oin = qn h
        float kth[4][4], oin[4][4];
#pragma unroll
        for (int r = 0; r < 4; r++)
#pragma unroll
            for (int c2 = 0; c2 < 4; c2++) { kth[r][c2] = 0.f; oin[r][c2] = 0.f; }
#pragma unroll 4
        for (int d = 0; d < 64; d++) {
            const float4 wv = *(const float4*)&X1[d * 64 + t0];
            const float4 qv = *(const float4*)&X2[d * PD + t0];
            const float4 hv = *(const float4*)&HB[d * 64 + e0];
            const float wa[4] = {wv.x, wv.y, wv.z, wv.w};
            const float qa2[4] = {qv.x, qv.y, qv.z, qv.w};
            const float hv4[4] = {hv.x, hv.y, hv.z, hv.w};
#pragma unroll
            for (int r = 0; r < 4; r++)
#pragma unroll
                for (int c2 = 0; c2 < 4; c2++) {
                    kth[r][c2] += wa[r] * hv4[c2];
                    oin[r][c2] += qa2[r] * hv4[c2];
                }
        }

        // epilogue: U^T tile from global (L2-hot), qn from X2
        float* oc = outg + qbase;
        float o4[4][4];
#pragma unroll
        for (int s = 0; s < 4; s++) {
            const float4 u4 = *(const float4*)(UTg + wbase + (size_t)(e0 + s) * 64 + t0);
            const float4 q4 = *(const float4*)&X2[(e0 + s) * PD + t0];
            o4[0][s] = q4.x * (u4.x - kth[0][s]) + oin[0][s];
            o4[1][s] = q4.y * (u4.y - kth[1][s]) + oin[1][s];
            o4[2][s] = q4.z * (u4.z - kth[2][s]) + oin[2][s];
            o4[3][s] = q4.w * (u4.w - kth[3][s]) + oin[3][s];
        }
#pragma unroll
        for (int r = 0; r < 4; r++)
            *(float4*)(oc + (size_t)(t0 + r) * 64 + e0) =
                make_float4(o4[r][0], o4[r][1], o4[r][2], o4[r][3]);
    }
}

extern "C" void kernel_launch(void* const* d_in, const int* in_sizes, int n_in,
                              void* d_out, int out_size, void* d_ws, size_t ws_size,
                              hipStream_t stream) {
    const float* q    = (const float*)d_in[0];
    const float* k    = (const float*)d_in[1];
    const float* v    = (const float*)d_in[2];
    const float* beta = (const float*)d_in[3];
    float* out = (float*)d_out;

    float* WTg   = (float*)d_ws;                              // [BH][NC][64][64] (W^T)
    float* UTg   = WTg + (size_t)BHn * NCC * Cc * Dd;         // [BH][NC][64][64] (U^T)
    float* wlast = UTg + (size_t)BHn * NCC * Cc * Dd;         // [BH][NC][64]
    float* ulast = wlast + (size_t)BHn * NCC * 64;            // [BH][NC][64]
    float* Uvg   = ulast + (size_t)BHn * NCC * 64;            // [BH][NC][64]

    kA<<<dim3(NCC, BHn), 256, 0, stream>>>(k, v, beta, WTg, UTg, wlast, ulast);
    kB<<<dim3(BHn), 256, 0, stream>>>(wlast, ulast, Uvg);
    kC<<<dim3(32, BHn), 256, 0, stream>>>(q, WTg, UTg, wlast, Uvg, out);
}